// Round 7
// baseline (493.615 us; speedup 1.0000x reference)
//
#include <hip/hip_runtime.h>
#include <math.h>

#define N_NODES 10000
#define N_EDGES 320000
#define TILES 5                 // 5 tiles x 32 edges = 160 edges per block
#define NBLK (N_EDGES / (32 * TILES))   // 2000 blocks

#define SQRT3F     1.7320508075688772f
#define INV_SQRT3F 0.5773502691896258f
#define INV_SQRT2F 0.7071067811865476f

typedef short bf16x8 __attribute__((ext_vector_type(8)));
typedef short b16x4  __attribute__((ext_vector_type(4)));
typedef float f32x4  __attribute__((ext_vector_type(4)));

static __device__ __forceinline__ unsigned short f2b(float f) {
    unsigned int u = __float_as_uint(f);
    unsigned int r = (u + 0x7fffu + ((u >> 16) & 1u)) >> 16;   // RNE
    return (unsigned short)r;
}
static __device__ __forceinline__ float b2f(unsigned short h) {
    return __uint_as_float(((unsigned int)h) << 16);
}

// ---------------------------------------------------------------------------
// Kernel 0: weights -> bf16, transposed to fragment-friendly [n][k] layout.
// ---------------------------------------------------------------------------
__global__ __launch_bounds__(256) void prep_weights(
    const float* __restrict__ Wfc1, const float* __restrict__ Wfc2,
    unsigned short* __restrict__ W1T, unsigned short* __restrict__ W2T)
{
    int idx = blockIdx.x * 256 + threadIdx.x;
    if (idx < 4096) {
        int n = idx >> 6, k = idx & 63;
        W1T[idx] = f2b(Wfc1[k * 64 + n]);
    } else if (idx < 18432) {
        int j = idx - 4096;
        int n = j >> 6, k = j & 63;
        W2T[j] = f2b(Wfc2[k * 224 + n]);
    }
}

// ---------------------------------------------------------------------------
// Kernel 1: per-node linear transforms into st_vt16[n][160] (bf16):
//   [0..63]    s_t = nf_s @ W_nl0
//   [64..159]  v_t TRANSPOSED: layout i*32+k
// ---------------------------------------------------------------------------
__global__ __launch_bounds__(256) void node_prep(
    const float* __restrict__ nf,
    const float* __restrict__ Wnl0,
    const float* __restrict__ Wnl1,
    unsigned short* __restrict__ st_vt16)
{
    int gid = blockIdx.x * blockDim.x + threadIdx.x;
    if (gid >= N_NODES * 160) return;
    int n = gid / 160;
    int j = gid - n * 160;
    const float* nfn = nf + (size_t)n * 160;

    float acc = 0.f;
    if (j < 64) {
        #pragma unroll 8
        for (int k = 0; k < 64; ++k) acc += nfn[k] * Wnl0[k * 64 + j];
    } else {
        int t = j - 64;
        int i = t >> 5, k = t & 31;
        #pragma unroll 8
        for (int m = 0; m < 32; ++m) acc += nfn[64 + m * 3 + i] * Wnl1[m * 32 + k];
    }
    st_vt16[(size_t)n * 160 + j] = f2b(acc);
}

// ---------------------------------------------------------------------------
// Sorting: histogram of src, exclusive scan, scatter to sorted arrays.
// ---------------------------------------------------------------------------
__global__ __launch_bounds__(256) void hist_kernel(
    const int* __restrict__ eidx, int* __restrict__ cnt)
{
    int e = blockIdx.x * 256 + threadIdx.x;
    if (e < N_EDGES) atomicAdd(&cnt[eidx[e]], 1);
}

__global__ __launch_bounds__(1024) void scan_kernel(
    const int* __restrict__ cnt, int* __restrict__ row_start)
{
    __shared__ int part[1024];
    const int t = threadIdx.x;
    const int CH = 10;
    int base = t * CH;
    int s = 0;
    for (int i = 0; i < CH; ++i) {
        int idx = base + i;
        if (idx < N_NODES) s += cnt[idx];
    }
    part[t] = s;
    __syncthreads();
    for (int off = 1; off < 1024; off <<= 1) {
        int v = (t >= off) ? part[t - off] : 0;
        __syncthreads();
        part[t] += v;
        __syncthreads();
    }
    int run = (t == 0) ? 0 : part[t - 1];
    for (int i = 0; i < CH; ++i) {
        int idx = base + i;
        if (idx < N_NODES) { row_start[idx] = run; run += cnt[idx]; }
    }
    if (t == 1023) row_start[N_NODES] = run;
}

__global__ __launch_bounds__(256) void scatter_kernel(
    const int* __restrict__ eidx, const float* __restrict__ edge_attr,
    const int* __restrict__ row_start,
    int* __restrict__ fill, int* __restrict__ order,
    int* __restrict__ src_srt, int* __restrict__ dst_srt,
    float* __restrict__ sh_srt)
{
    int e = blockIdx.x * 256 + threadIdx.x;
    if (e >= N_EDGES) return;
    int s = eidx[e];
    int p = atomicAdd(&fill[s], 1) + row_start[s];
    order[p] = e;
    src_srt[p] = s;
    dst_srt[p] = eidx[N_EDGES + e];
    float x = edge_attr[(size_t)e * 3 + 0];
    float y = edge_attr[(size_t)e * 3 + 1];
    float z = edge_attr[(size_t)e * 3 + 2];
    float inv = SQRT3F / sqrtf(x * x + y * y + z * z);
    sh_srt[(size_t)p * 4 + 0] = x * inv;
    sh_srt[(size_t)p * 4 + 1] = y * inv;
    sh_srt[(size_t)p * 4 + 2] = z * inv;
    sh_srt[(size_t)p * 4 + 3] = 0.f;
}

// ---------------------------------------------------------------------------
// Kernel 2: multi-tile MFMA edge MLP + message + segmented scatter.
// 2000 blocks x 256 thr; 5 tiles of 32 sorted edges per block.
// Weights in registers once per block. NO df staging: phase-3 x-operands
// read directly from L2-resident st_vt16 (3.2 MB). LDS ~26.5 KB -> 6 blk/CU.
// ---------------------------------------------------------------------------
__global__ __launch_bounds__(256, 6) void edge_conv(
    const unsigned short* __restrict__ W1T,
    const unsigned short* __restrict__ W2T,
    const int* __restrict__ order,
    const int* __restrict__ src_srt,
    const int* __restrict__ dst_srt,
    const float* __restrict__ sh_srt,
    const float* __restrict__ edge_feature,
    const unsigned short* __restrict__ st_vt16,
    float* __restrict__ agg)
{
    __shared__ __align__(16) unsigned short A1[32 * 64];      // 4 KB (swizzled)
    __shared__ __align__(16) unsigned short Hs[32 * 64];      // 4 KB (swizzled)
    __shared__ __align__(16) unsigned short w_s[32 * 224];    // 14 KB
    __shared__ int   eid_s[160];
    __shared__ int   src_s[160];
    __shared__ int   dst_s[160];
    __shared__ float sh_s[160][4];

    const int tid  = threadIdx.x;
    const int lane = tid & 63;
    const int wv   = tid >> 6;
    const int l15  = lane & 15;
    const int g    = lane >> 4;
    const int p0   = blockIdx.x * (32 * TILES);

    // ---- weight fragments (once per block) ----
    bf16x8 w1b0 = *reinterpret_cast<const bf16x8*>(&W1T[(wv * 16 + l15) * 64 + g * 8]);
    bf16x8 w1b1 = *reinterpret_cast<const bf16x8*>(&W1T[(wv * 16 + l15) * 64 + 32 + g * 8]);
    bf16x8 w2b0[4], w2b1[4];
    #pragma unroll
    for (int ii = 0; ii < 4; ++ii) {
        int nt = wv * 4 + ii;    // 0..15 (rows 224..255 of W2T are padding)
        w2b0[ii] = *reinterpret_cast<const bf16x8*>(&W2T[(nt * 16 + l15) * 64 + g * 8]);
        w2b1[ii] = *reinterpret_cast<const bf16x8*>(&W2T[(nt * 16 + l15) * 64 + 32 + g * 8]);
    }

    // ---- block metadata (coalesced, once) ----
    if (tid < 32 * TILES) {
        int p = p0 + tid;
        eid_s[tid] = order[p];
        src_s[tid] = src_srt[p];
        dst_s[tid] = dst_srt[p];
        *reinterpret_cast<f32x4*>(&sh_s[tid][0]) =
            *reinterpret_cast<const f32x4*>(&sh_srt[(size_t)p * 4]);
    }
    __syncthreads();

    // ---- phase-3 region setup (fixed per thread) ----
    const int tid2 = tid & 127;
    int region, cb, iv;
    if (tid2 < 48)       { region = 0; cb = tid2 & 15;        iv = tid2 >> 4; }
    else if (tid2 < 64)  { region = 1; cb = tid2 - 48;        iv = 0; }
    else if (tid2 < 88)  { region = 2; cb = (tid2 - 64) & 7;  iv = (tid2 - 64) >> 3; }
    else if (tid2 < 112) { region = 3; cb = (tid2 - 88) & 7;  iv = (tid2 - 88) >> 3; }
    else if (tid2 < 120) { region = 4; cb = tid2 - 112;       iv = 0; }
    else                 { region = 5; cb = 0; iv = 0; }
    int rbase = 0, woff = 0, doff = 0;
    if (region == 0)      { rbase = 96 + iv * 64 + 4 * cb;  woff = 64 + 4 * cb;  doff = 4 * cb; }
    else if (region == 1) { rbase = 4 * cb;                 woff = 4 * cb;       doff = 4 * cb; }
    else if (region == 2) { rbase = 288 + iv * 32 + 4 * cb; woff = 128 + 4 * cb; doff = 64 + iv * 32 + 4 * cb; }
    else if (region == 3) { rbase = 384 + iv * 32 + 4 * cb; woff = 192 + 4 * cb; }
    else if (region == 4) { rbase = 64 + 4 * cb;            woff = 160 + 4 * cb; }
    int i1 = iv + 1; if (i1 == 3) i1 = 0;
    int i2 = 3 - iv - i1;

    f32x4 acc = {0.f, 0.f, 0.f, 0.f};
    int cur = src_s[(tid >> 7) * 16];

    // ---- ef staging (reg prefetch one tile ahead) ----
    f32x4 efr[2];
    auto load_ef = [&](int t) {
        int ebase = t * 32;
        #pragma unroll
        for (int r = 0; r < 2; ++r) {
            int q = tid + r * 256;
            int el = q >> 4, qf = q & 15;
            efr[r] = *reinterpret_cast<const f32x4*>(
                edge_feature + (size_t)eid_s[ebase + el] * 64 + qf * 4);
        }
    };
    auto write_ef = [&]() {
        #pragma unroll
        for (int r = 0; r < 2; ++r) {
            int q = tid + r * 256;
            int el = q >> 4, f0 = (q & 15) * 4;
            b16x4 h;
            #pragma unroll
            for (int j = 0; j < 4; ++j) h[j] = (short)f2b(efr[r][j]);
            *reinterpret_cast<b16x4*>(&A1[el * 64 + (f0 ^ ((el & 7) << 3))]) = h;
        }
    };

    // ---- prologue ----
    load_ef(0);

    for (int t = 0; t < TILES; ++t) {
        // A: commit prefetched ef(t) into A1
        write_ef();
        __syncthreads();

        // B: prefetch ef(t+1)
        if (t < TILES - 1) load_ef(t + 1);

        // C: GEMM1  Hs = relu(A1 @ Wfc1)
        {
            const int nt = wv;
            #pragma unroll
            for (int mt = 0; mt < 2; ++mt) {
                f32x4 c4 = {0.f, 0.f, 0.f, 0.f};
                int ra = mt * 16 + l15;
                int sw = (ra & 7) << 3;
                bf16x8 a0 = *reinterpret_cast<const bf16x8*>(&A1[ra * 64 + ((g * 8) ^ sw)]);
                bf16x8 a1 = *reinterpret_cast<const bf16x8*>(&A1[ra * 64 + ((32 + g * 8) ^ sw)]);
                c4 = __builtin_amdgcn_mfma_f32_16x16x32_bf16(a0, w1b0, c4, 0, 0, 0);
                c4 = __builtin_amdgcn_mfma_f32_16x16x32_bf16(a1, w1b1, c4, 0, 0, 0);
                #pragma unroll
                for (int r = 0; r < 4; ++r) {
                    int row = mt * 16 + g * 4 + r;
                    int col = nt * 16 + l15;
                    Hs[row * 64 + (col ^ ((row & 7) << 3))] = f2b(fmaxf(c4[r], 0.f));
                }
            }
        }
        __syncthreads();

        // D: GEMM2  w_s = Hs @ Wfc2 (16 strips unrolled, stores masked nt<14)
        {
            #pragma unroll
            for (int ii = 0; ii < 4; ++ii) {
                int nt = wv * 4 + ii;
                #pragma unroll
                for (int mt = 0; mt < 2; ++mt) {
                    f32x4 c4 = {0.f, 0.f, 0.f, 0.f};
                    int ra = mt * 16 + l15;
                    int sw = (ra & 7) << 3;
                    bf16x8 a0 = *reinterpret_cast<const bf16x8*>(&Hs[ra * 64 + ((g * 8) ^ sw)]);
                    bf16x8 a1 = *reinterpret_cast<const bf16x8*>(&Hs[ra * 64 + ((32 + g * 8) ^ sw)]);
                    c4 = __builtin_amdgcn_mfma_f32_16x16x32_bf16(a0, w2b0[ii], c4, 0, 0, 0);
                    c4 = __builtin_amdgcn_mfma_f32_16x16x32_bf16(a1, w2b1[ii], c4, 0, 0, 0);
                    if (nt < 14) {
                        #pragma unroll
                        for (int r = 0; r < 4; ++r) {
                            int row = mt * 16 + g * 4 + r;
                            w_s[row * 224 + nt * 16 + l15] = f2b(c4[r]);
                        }
                    }
                }
            }
        }
        __syncthreads();

        // E: phase 3 — messages for tile t; x-operands direct from L2
        if (region < 5) {
            const int e0l = (tid >> 7) * 16;
            #pragma unroll 4
            for (int j2 = 0; j2 < 16; ++j2) {
                int el = e0l + j2;
                int eg = t * 32 + el;
                int s = src_s[eg];
                if (s != cur) {
                    #pragma unroll
                    for (int j = 0; j < 4; ++j)
                        atomicAdd(&agg[(size_t)cur * 480 + rbase + j], acc[j]);
                    acc = (f32x4){0.f, 0.f, 0.f, 0.f};
                    cur = s;
                }
                const unsigned short* xg = st_vt16 + (size_t)dst_s[eg] * 160;
                const unsigned short* we = &w_s[el * 224];
                b16x4 w = *reinterpret_cast<const b16x4*>(we + woff);
                if (region == 0) {
                    b16x4 x = *reinterpret_cast<const b16x4*>(xg + doff);
                    float sh = sh_s[eg][iv];
                    #pragma unroll
                    for (int j = 0; j < 4; ++j)
                        acc[j] += b2f((unsigned short)w[j]) * b2f((unsigned short)x[j]) * sh;
                } else if (region == 1 || region == 2) {
                    b16x4 x = *reinterpret_cast<const b16x4*>(xg + doff);
                    #pragma unroll
                    for (int j = 0; j < 4; ++j)
                        acc[j] += b2f((unsigned short)w[j]) * b2f((unsigned short)x[j]);
                } else if (region == 3) {
                    b16x4 xA = *reinterpret_cast<const b16x4*>(xg + 64 + i1 * 32 + 4 * cb);
                    b16x4 xB = *reinterpret_cast<const b16x4*>(xg + 64 + i2 * 32 + 4 * cb);
                    float shA = sh_s[eg][i1], shB = sh_s[eg][i2];
                    #pragma unroll
                    for (int j = 0; j < 4; ++j)
                        acc[j] += b2f((unsigned short)w[j]) *
                                  (b2f((unsigned short)xA[j]) * shB -
                                   b2f((unsigned short)xB[j]) * shA) * INV_SQRT2F;
                } else {
                    b16x4 x0 = *reinterpret_cast<const b16x4*>(xg + 64 + 4 * cb);
                    b16x4 x1 = *reinterpret_cast<const b16x4*>(xg + 96 + 4 * cb);
                    b16x4 x2 = *reinterpret_cast<const b16x4*>(xg + 128 + 4 * cb);
                    float s0 = sh_s[eg][0], s1 = sh_s[eg][1], s2 = sh_s[eg][2];
                    #pragma unroll
                    for (int j = 0; j < 4; ++j)
                        acc[j] += b2f((unsigned short)w[j]) *
                                  (b2f((unsigned short)x0[j]) * s0 +
                                   b2f((unsigned short)x1[j]) * s1 +
                                   b2f((unsigned short)x2[j]) * s2) * INV_SQRT3F;
                }
            }
        }
    }

    // epilogue flush
    if (region < 5) {
        #pragma unroll
        for (int j = 0; j < 4; ++j)
            atomicAdd(&agg[(size_t)cur * 480 + rbase + j], acc[j]);
    }
}

// ---------------------------------------------------------------------------
// Kernel 3: per-node output transform + gating (reads permuted agg layout).
// ---------------------------------------------------------------------------
__global__ __launch_bounds__(128) void out_kernel(
    const float* __restrict__ agg,
    const float* __restrict__ nf,
    const float* __restrict__ Wskip0,
    const float* __restrict__ Wskip1,
    const float* __restrict__ Wout_s,
    const float* __restrict__ Wout_v,
    float* __restrict__ out)
{
    __shared__ float aggl[480];
    __shared__ float os_s[96];
    const int n = blockIdx.x;
    const int tid = threadIdx.x;
    const float* nfn = nf + (size_t)n * 160;

    for (int idx = tid; idx < 480; idx += 128)
        aggl[idx] = agg[(size_t)n * 480 + idx] * (1.f / 32.f);
    __syncthreads();

    if (tid < 96) {
        float acc = 0.f;
        #pragma unroll 8
        for (int k = 0; k < 64; ++k) acc += nfn[k] * Wskip0[k * 96 + tid];
        for (int r = 0; r < 96; ++r) acc += aggl[r] * Wout_s[r * 96 + tid];
        os_s[tid] = acc;
    }
    __syncthreads();

    if (tid < 64) {
        float x = os_s[tid];
        out[(size_t)n * 160 + tid] = x / (1.f + expf(-x));  // silu
    }
    if (tid < 96) {
        int t = tid;
        int k = t / 3, i = t - 3 * k;
        float acc = 0.f;
        #pragma unroll 8
        for (int m = 0; m < 32; ++m) acc += nfn[64 + m * 3 + i] * Wskip1[m * 32 + k];
        #pragma unroll 8
        for (int m = 0; m < 64; ++m) acc += aggl[96 + i * 64 + m] * Wout_v[m * 32 + k];
        #pragma unroll 8
        for (int m = 0; m < 32; ++m) acc += aggl[288 + i * 32 + m] * Wout_v[(64 + m) * 32 + k];
        #pragma unroll 8
        for (int m = 0; m < 32; ++m) acc += aggl[384 + i * 32 + m] * Wout_v[(96 + m) * 32 + k];
        float g = os_s[64 + k];
        g = 1.f / (1.f + expf(-g));  // sigmoid gate
        out[(size_t)n * 160 + 64 + t] = g * acc;
    }
}

// ---------------------------------------------------------------------------
extern "C" void kernel_launch(void* const* d_in, const int* in_sizes, int n_in,
                              void* d_out, int out_size, void* d_ws, size_t ws_size,
                              hipStream_t stream)
{
    const float* nf     = (const float*)d_in[0];
    const float* ea     = (const float*)d_in[1];
    const float* ef     = (const float*)d_in[2];
    const float* Wskip0 = (const float*)d_in[3];
    const float* Wskip1 = (const float*)d_in[4];
    const float* Wnl0   = (const float*)d_in[5];
    const float* Wnl1   = (const float*)d_in[6];
    const float* Wfc1   = (const float*)d_in[7];
    const float* Wfc2   = (const float*)d_in[8];
    const float* Wout_s = (const float*)d_in[9];
    const float* Wout_v = (const float*)d_in[10];
    const int*   eidx   = (const int*)d_in[11];
    float* out = (float*)d_out;

    // workspace layout (16B-aligned sections), ~31.5 MB total
    int*   cnt       = (int*)d_ws;                        // 10000
    int*   fill      = cnt + 10000;                       // 10000
    int*   row_start = fill + 10000;                      // 10004
    int*   order     = row_start + 10004;                 // 320000
    int*   src_srt   = order + 320000;                    // 320000
    int*   dst_srt   = src_srt + 320000;                  // 320000
    float* sh_srt    = (float*)(dst_srt + 320000);        // 1,280,000
    float* agg       = sh_srt + 1280000;                  // 4,800,000
    unsigned short* st_vt16 = (unsigned short*)(agg + 4800000); // 1,600,000 shorts
    unsigned short* W1T = st_vt16 + 1600000;              // 4,096 shorts
    unsigned short* W2T = W1T + 4096;                     // 16,384 shorts (256 rows, 224 valid)

    hipMemsetAsync(cnt, 0, 20000 * sizeof(int), stream);               // cnt+fill
    hipMemsetAsync(agg, 0, (size_t)N_NODES * 480 * sizeof(float), stream);

    prep_weights<<<72, 256, 0, stream>>>(Wfc1, Wfc2, W1T, W2T);

    node_prep<<<(N_NODES * 160 + 255) / 256, 256, 0, stream>>>(
        nf, Wnl0, Wnl1, st_vt16);

    hist_kernel<<<(N_EDGES + 255) / 256, 256, 0, stream>>>(eidx, cnt);
    scan_kernel<<<1, 1024, 0, stream>>>(cnt, row_start);
    scatter_kernel<<<(N_EDGES + 255) / 256, 256, 0, stream>>>(
        eidx, ea, row_start, fill, order, src_srt, dst_srt, sh_srt);

    edge_conv<<<NBLK, 256, 0, stream>>>(
        W1T, W2T, order, src_srt, dst_srt, sh_srt, ef, st_vt16, agg);

    out_kernel<<<N_NODES, 128, 0, stream>>>(
        agg, nf, Wskip0, Wskip1, Wout_s, Wout_v, out);
}

// Round 8
// 409.776 us; speedup vs baseline: 1.2046x; 1.2046x over previous
//
#include <hip/hip_runtime.h>
#include <math.h>

#define N_NODES 10000
#define N_EDGES 320000
#define TILES 5                 // 5 tiles x 32 edges = 160 edges per block
#define NBLK (N_EDGES / (32 * TILES))   // 2000 blocks

#define SQRT3F     1.7320508075688772f
#define INV_SQRT3F 0.5773502691896258f
#define INV_SQRT2F 0.7071067811865476f

typedef short bf16x8 __attribute__((ext_vector_type(8)));
typedef short b16x4  __attribute__((ext_vector_type(4)));
typedef float f32x4  __attribute__((ext_vector_type(4)));
typedef unsigned int u32;

static __device__ __forceinline__ unsigned short f2b(float f) {
    unsigned int u = __float_as_uint(f);
    unsigned int r = (u + 0x7fffu + ((u >> 16) & 1u)) >> 16;   // RNE
    return (unsigned short)r;
}
static __device__ __forceinline__ float b2f(unsigned short h) {
    return __uint_as_float(((unsigned int)h) << 16);
}

// direct global->LDS 16B copy (wave-uniform LDS base + lane*16; per-lane global src)
static __device__ __forceinline__ void gl_lds16(const void* g, void* l) {
    __builtin_amdgcn_global_load_lds(
        (const __attribute__((address_space(1))) u32*)g,
        (__attribute__((address_space(3))) u32*)l,
        16, 0, 0);
}

// ---------------------------------------------------------------------------
// Kernel P: merged prep — node transforms (blocks 0..6249), src histogram
// (6250..7499), weight conversion (7500..7571).
//   st_vt16[n][160] bf16: [0..63] s_t = nf_s @ W_nl0
//                         [64..159] v_t TRANSPOSED layout i*32+k
// ---------------------------------------------------------------------------
__global__ __launch_bounds__(256) void prep_kernel(
    const float* __restrict__ nf,
    const float* __restrict__ Wnl0,
    const float* __restrict__ Wnl1,
    const float* __restrict__ Wfc1,
    const float* __restrict__ Wfc2,
    const int* __restrict__ eidx,
    unsigned short* __restrict__ st_vt16,
    unsigned short* __restrict__ W1T,
    unsigned short* __restrict__ W2T,
    int* __restrict__ cnt)
{
    const int b = blockIdx.x;
    const int tid = threadIdx.x;
    if (b < 6250) {
        int gid = b * 256 + tid;
        if (gid >= N_NODES * 160) return;
        int n = gid / 160;
        int j = gid - n * 160;
        const float* nfn = nf + (size_t)n * 160;
        float acc = 0.f;
        if (j < 64) {
            #pragma unroll 8
            for (int k = 0; k < 64; ++k) acc += nfn[k] * Wnl0[k * 64 + j];
        } else {
            int t = j - 64;
            int i = t >> 5, k = t & 31;
            #pragma unroll 8
            for (int m = 0; m < 32; ++m) acc += nfn[64 + m * 3 + i] * Wnl1[m * 32 + k];
        }
        st_vt16[(size_t)n * 160 + j] = f2b(acc);
    } else if (b < 7500) {
        int e = (b - 6250) * 256 + tid;
        if (e < N_EDGES) atomicAdd(&cnt[eidx[e]], 1);
    } else {
        int idx = (b - 7500) * 256 + tid;
        if (idx < 4096) {
            int n = idx >> 6, k = idx & 63;
            W1T[idx] = f2b(Wfc1[k * 64 + n]);
        } else if (idx < 18432) {
            int j = idx - 4096;
            int n = j >> 6, k = j & 63;
            W2T[j] = f2b(Wfc2[k * 224 + n]);
        }
    }
}

// ---------------------------------------------------------------------------
// scan + scatter (sorting by src)
// ---------------------------------------------------------------------------
__global__ __launch_bounds__(1024) void scan_kernel(
    const int* __restrict__ cnt, int* __restrict__ row_start)
{
    __shared__ int part[1024];
    const int t = threadIdx.x;
    const int CH = 10;
    int base = t * CH;
    int s = 0;
    for (int i = 0; i < CH; ++i) {
        int idx = base + i;
        if (idx < N_NODES) s += cnt[idx];
    }
    part[t] = s;
    __syncthreads();
    for (int off = 1; off < 1024; off <<= 1) {
        int v = (t >= off) ? part[t - off] : 0;
        __syncthreads();
        part[t] += v;
        __syncthreads();
    }
    int run = (t == 0) ? 0 : part[t - 1];
    for (int i = 0; i < CH; ++i) {
        int idx = base + i;
        if (idx < N_NODES) { row_start[idx] = run; run += cnt[idx]; }
    }
    if (t == 1023) row_start[N_NODES] = run;
}

__global__ __launch_bounds__(256) void scatter_kernel(
    const int* __restrict__ eidx, const float* __restrict__ edge_attr,
    const int* __restrict__ row_start,
    int* __restrict__ fill, int* __restrict__ order,
    int* __restrict__ src_srt, int* __restrict__ dst_srt,
    float* __restrict__ sh_srt)
{
    int e = blockIdx.x * 256 + threadIdx.x;
    if (e >= N_EDGES) return;
    int s = eidx[e];
    int p = atomicAdd(&fill[s], 1) + row_start[s];
    order[p] = e;
    src_srt[p] = s;
    dst_srt[p] = eidx[N_EDGES + e];
    float x = edge_attr[(size_t)e * 3 + 0];
    float y = edge_attr[(size_t)e * 3 + 1];
    float z = edge_attr[(size_t)e * 3 + 2];
    float inv = SQRT3F / sqrtf(x * x + y * y + z * z);
    sh_srt[(size_t)p * 4 + 0] = x * inv;
    sh_srt[(size_t)p * 4 + 1] = y * inv;
    sh_srt[(size_t)p * 4 + 2] = z * inv;
    sh_srt[(size_t)p * 4 + 3] = 0.f;
}

// ---------------------------------------------------------------------------
// Kernel A: pure MFMA MLP pipeline. Writes w_srt[p][224] bf16 coalesced.
// 2000 blocks x 256 thr; 5 tiles of 32 sorted edges.
// ---------------------------------------------------------------------------
__global__ __launch_bounds__(256, 5) void edge_mlp(
    const unsigned short* __restrict__ W1T,
    const unsigned short* __restrict__ W2T,
    const int* __restrict__ order,
    const float* __restrict__ edge_feature,
    unsigned short* __restrict__ w_srt)
{
    __shared__ __align__(16) unsigned short A1[32 * 64];      // 4 KB (swizzled)
    __shared__ __align__(16) unsigned short Hs[32 * 64];      // 4 KB (swizzled)
    __shared__ __align__(16) unsigned short w_s[32 * 224];    // 14 KB
    __shared__ int eid_s[160];

    const int tid  = threadIdx.x;
    const int lane = tid & 63;
    const int wv   = tid >> 6;
    const int l15  = lane & 15;
    const int g    = lane >> 4;
    const int p0   = blockIdx.x * (32 * TILES);

    // weight fragments, once per block
    bf16x8 w1b0 = *reinterpret_cast<const bf16x8*>(&W1T[(wv * 16 + l15) * 64 + g * 8]);
    bf16x8 w1b1 = *reinterpret_cast<const bf16x8*>(&W1T[(wv * 16 + l15) * 64 + 32 + g * 8]);
    bf16x8 w2b0[4], w2b1[4];
    #pragma unroll
    for (int ii = 0; ii < 4; ++ii) {
        int nt = wv * 4 + ii;
        w2b0[ii] = *reinterpret_cast<const bf16x8*>(&W2T[(nt * 16 + l15) * 64 + g * 8]);
        w2b1[ii] = *reinterpret_cast<const bf16x8*>(&W2T[(nt * 16 + l15) * 64 + 32 + g * 8]);
    }

    if (tid < 32 * TILES) eid_s[tid] = order[p0 + tid];
    __syncthreads();

    f32x4 efr[2];
    auto load_ef = [&](int t) {
        int ebase = t * 32;
        #pragma unroll
        for (int r = 0; r < 2; ++r) {
            int q = tid + r * 256;
            int el = q >> 4, qf = q & 15;
            efr[r] = *reinterpret_cast<const f32x4*>(
                edge_feature + (size_t)eid_s[ebase + el] * 64 + qf * 4);
        }
    };
    auto write_ef = [&]() {
        #pragma unroll
        for (int r = 0; r < 2; ++r) {
            int q = tid + r * 256;
            int el = q >> 4, f0 = (q & 15) * 4;
            b16x4 h;
            #pragma unroll
            for (int j = 0; j < 4; ++j) h[j] = (short)f2b(efr[r][j]);
            *reinterpret_cast<b16x4*>(&A1[el * 64 + (f0 ^ ((el & 7) << 3))]) = h;
        }
    };

    load_ef(0);

    for (int t = 0; t < TILES; ++t) {
        write_ef();
        __syncthreads();
        if (t < TILES - 1) load_ef(t + 1);

        // GEMM1: Hs = relu(A1 @ Wfc1)
        {
            const int nt = wv;
            #pragma unroll
            for (int mt = 0; mt < 2; ++mt) {
                f32x4 c4 = {0.f, 0.f, 0.f, 0.f};
                int ra = mt * 16 + l15;
                int sw = (ra & 7) << 3;
                bf16x8 a0 = *reinterpret_cast<const bf16x8*>(&A1[ra * 64 + ((g * 8) ^ sw)]);
                bf16x8 a1 = *reinterpret_cast<const bf16x8*>(&A1[ra * 64 + ((32 + g * 8) ^ sw)]);
                c4 = __builtin_amdgcn_mfma_f32_16x16x32_bf16(a0, w1b0, c4, 0, 0, 0);
                c4 = __builtin_amdgcn_mfma_f32_16x16x32_bf16(a1, w1b1, c4, 0, 0, 0);
                #pragma unroll
                for (int r = 0; r < 4; ++r) {
                    int row = mt * 16 + g * 4 + r;
                    int col = nt * 16 + l15;
                    Hs[row * 64 + (col ^ ((row & 7) << 3))] = f2b(fmaxf(c4[r], 0.f));
                }
            }
        }
        __syncthreads();

        // GEMM2: w_s = Hs @ Wfc2 (stores masked nt<14)
        {
            #pragma unroll
            for (int ii = 0; ii < 4; ++ii) {
                int nt = wv * 4 + ii;
                #pragma unroll
                for (int mt = 0; mt < 2; ++mt) {
                    f32x4 c4 = {0.f, 0.f, 0.f, 0.f};
                    int ra = mt * 16 + l15;
                    int sw = (ra & 7) << 3;
                    bf16x8 a0 = *reinterpret_cast<const bf16x8*>(&Hs[ra * 64 + ((g * 8) ^ sw)]);
                    bf16x8 a1 = *reinterpret_cast<const bf16x8*>(&Hs[ra * 64 + ((32 + g * 8) ^ sw)]);
                    c4 = __builtin_amdgcn_mfma_f32_16x16x32_bf16(a0, w2b0[ii], c4, 0, 0, 0);
                    c4 = __builtin_amdgcn_mfma_f32_16x16x32_bf16(a1, w2b1[ii], c4, 0, 0, 0);
                    if (nt < 14) {
                        #pragma unroll
                        for (int r = 0; r < 4; ++r) {
                            int row = mt * 16 + g * 4 + r;
                            w_s[row * 224 + nt * 16 + l15] = f2b(c4[r]);
                        }
                    }
                }
            }
        }
        __syncthreads();

        // coalesced copy-out: 32x224 u16 = 896 x 16B
        {
            const size_t gbase = (size_t)(p0 + t * 32) * 224;
            for (int idx = tid; idx < 896; idx += 256) {
                *reinterpret_cast<f32x4*>(&w_srt[gbase + idx * 8]) =
                    *reinterpret_cast<const f32x4*>(&w_s[idx * 8]);
            }
        }
        // copy-out drains at the barrier after next write_ef (before GEMM2 rewrites w_s)
    }
}

// ---------------------------------------------------------------------------
// Kernel B: pure streaming messages + segmented scatter. No MFMA, no GEMM
// barriers. df staged via global_load_lds (dbuf, issued early / drained at
// the end-of-tile barrier). w read sequentially from w_srt. 6 blocks/CU.
// agg layout (PERMUTED vector regions, i-major):
//   [0:64) 0a | [64:96) 0b | [96:288) 1a: 96+i*64+c | [288:384) 1b | [384:480) 1c
// ---------------------------------------------------------------------------
__global__ __launch_bounds__(256, 6) void edge_msg(
    const int* __restrict__ src_srt,
    const int* __restrict__ dst_srt,
    const float* __restrict__ sh_srt,
    const unsigned short* __restrict__ w_srt,
    const unsigned short* __restrict__ st_vt16,
    float* __restrict__ agg)
{
    __shared__ __align__(16) unsigned short df[2][32 * 160];  // 2 x 10 KB
    __shared__ int   src_s[160];
    __shared__ int   dst_s[160];
    __shared__ float sh_s[160][4];

    // chunked XCD remap (2000 = 8 * 250): neighbor blocks share an XCD L2
    const int bid = (blockIdx.x & 7) * (NBLK / 8) + (blockIdx.x >> 3);
    const int tid = threadIdx.x;
    const int p0  = bid * (32 * TILES);

    if (tid < 32 * TILES) {
        int p = p0 + tid;
        src_s[tid] = src_srt[p];
        dst_s[tid] = dst_srt[p];
        *reinterpret_cast<f32x4*>(&sh_s[tid][0]) =
            *reinterpret_cast<const f32x4*>(&sh_srt[(size_t)p * 4]);
    }
    __syncthreads();

    // region setup (fixed per thread)
    const int tid2 = tid & 127;
    int region, cb, iv;
    if (tid2 < 48)       { region = 0; cb = tid2 & 15;        iv = tid2 >> 4; }
    else if (tid2 < 64)  { region = 1; cb = tid2 - 48;        iv = 0; }
    else if (tid2 < 88)  { region = 2; cb = (tid2 - 64) & 7;  iv = (tid2 - 64) >> 3; }
    else if (tid2 < 112) { region = 3; cb = (tid2 - 88) & 7;  iv = (tid2 - 88) >> 3; }
    else if (tid2 < 120) { region = 4; cb = tid2 - 112;       iv = 0; }
    else                 { region = 5; cb = 0; iv = 0; }
    int rbase = 0, woff = 0, doff = 0;
    if (region == 0)      { rbase = 96 + iv * 64 + 4 * cb;  woff = 64 + 4 * cb;  doff = 4 * cb; }
    else if (region == 1) { rbase = 4 * cb;                 woff = 4 * cb;       doff = 4 * cb; }
    else if (region == 2) { rbase = 288 + iv * 32 + 4 * cb; woff = 128 + 4 * cb; doff = 64 + iv * 32 + 4 * cb; }
    else if (region == 3) { rbase = 384 + iv * 32 + 4 * cb; woff = 192 + 4 * cb; }
    else if (region == 4) { rbase = 64 + 4 * cb;            woff = 160 + 4 * cb; }
    int i1 = iv + 1; if (i1 == 3) i1 = 0;
    int i2 = 3 - iv - i1;

    auto issue_df = [&](int t, int b) {
        int ebase = t * 32;
        #pragma unroll
        for (int r = 0; r < 3; ++r) {
            int idx = tid + r * 256;
            if (idx < 640) {                       // waves fully on/off (uniform)
                int el = idx / 20, off = idx - el * 20;
                gl_lds16(st_vt16 + (size_t)dst_s[ebase + el] * 160 + off * 8,
                         &df[b][idx * 8]);
            }
        }
    };

    f32x4 acc = {0.f, 0.f, 0.f, 0.f};
    int cur = src_s[(tid >> 7) * 16];

    issue_df(0, 0);
    __syncthreads();      // df(0) landed

    for (int t = 0; t < TILES; ++t) {
        const int b = t & 1;
        if (t < TILES - 1) issue_df(t + 1, b ^ 1);   // lands by end-of-tile barrier

        if (region < 5) {
            const int e0l = (tid >> 7) * 16;
            #pragma unroll 4
            for (int j2 = 0; j2 < 16; ++j2) {
                int el = e0l + j2;
                int eg = t * 32 + el;
                int s = src_s[eg];
                if (s != cur) {
                    #pragma unroll
                    for (int j = 0; j < 4; ++j)
                        atomicAdd(&agg[(size_t)cur * 480 + rbase + j], acc[j]);
                    acc = (f32x4){0.f, 0.f, 0.f, 0.f};
                    cur = s;
                }
                const unsigned short* dfp = &df[b][el * 160];
                const unsigned short* we  = w_srt + (size_t)(p0 + eg) * 224;
                b16x4 w = *reinterpret_cast<const b16x4*>(we + woff);
                if (region == 0) {
                    b16x4 x = *reinterpret_cast<const b16x4*>(dfp + doff);
                    float sh = sh_s[eg][iv];
                    #pragma unroll
                    for (int j = 0; j < 4; ++j)
                        acc[j] += b2f((unsigned short)w[j]) * b2f((unsigned short)x[j]) * sh;
                } else if (region == 1 || region == 2) {
                    b16x4 x = *reinterpret_cast<const b16x4*>(dfp + doff);
                    #pragma unroll
                    for (int j = 0; j < 4; ++j)
                        acc[j] += b2f((unsigned short)w[j]) * b2f((unsigned short)x[j]);
                } else if (region == 3) {
                    b16x4 xA = *reinterpret_cast<const b16x4*>(dfp + 64 + i1 * 32 + 4 * cb);
                    b16x4 xB = *reinterpret_cast<const b16x4*>(dfp + 64 + i2 * 32 + 4 * cb);
                    float shA = sh_s[eg][i1], shB = sh_s[eg][i2];
                    #pragma unroll
                    for (int j = 0; j < 4; ++j)
                        acc[j] += b2f((unsigned short)w[j]) *
                                  (b2f((unsigned short)xA[j]) * shB -
                                   b2f((unsigned short)xB[j]) * shA) * INV_SQRT2F;
                } else {
                    b16x4 x0 = *reinterpret_cast<const b16x4*>(dfp + 64 + 4 * cb);
                    b16x4 x1 = *reinterpret_cast<const b16x4*>(dfp + 96 + 4 * cb);
                    b16x4 x2 = *reinterpret_cast<const b16x4*>(dfp + 128 + 4 * cb);
                    float s0 = sh_s[eg][0], s1 = sh_s[eg][1], s2 = sh_s[eg][2];
                    #pragma unroll
                    for (int j = 0; j < 4; ++j)
                        acc[j] += b2f((unsigned short)w[j]) *
                                  (b2f((unsigned short)x0[j]) * s0 +
                                   b2f((unsigned short)x1[j]) * s1 +
                                   b2f((unsigned short)x2[j]) * s2) * INV_SQRT3F;
                }
            }
        }
        __syncthreads();   // drains df(t+1) loads; df(b) free for reuse
    }

    if (region < 5) {
        #pragma unroll
        for (int j = 0; j < 4; ++j)
            atomicAdd(&agg[(size_t)cur * 480 + rbase + j], acc[j]);
    }
}

// ---------------------------------------------------------------------------
// Fallback: round-6 fused kernel (used only if ws_size can't hold w_srt).
// ---------------------------------------------------------------------------
__global__ __launch_bounds__(256, 3) void edge_conv_fused(
    const unsigned short* __restrict__ W1T,
    const unsigned short* __restrict__ W2T,
    const int* __restrict__ order,
    const int* __restrict__ src_srt,
    const int* __restrict__ dst_srt,
    const float* __restrict__ sh_srt,
    const float* __restrict__ edge_feature,
    const unsigned short* __restrict__ st_vt16,
    float* __restrict__ agg)
{
    __shared__ __align__(16) unsigned short A1[32 * 64];
    __shared__ __align__(16) unsigned short Hs[32 * 64];
    __shared__ __align__(16) unsigned short w_s[32 * 224];
    __shared__ __align__(16) unsigned short df[2][32 * 160];
    __shared__ int   eid_s[160];
    __shared__ int   src_s[160];
    __shared__ int   dst_s[160];
    __shared__ float sh_s[160][4];

    const int tid  = threadIdx.x;
    const int lane = tid & 63;
    const int wv   = tid >> 6;
    const int l15  = lane & 15;
    const int g    = lane >> 4;
    const int p0   = blockIdx.x * (32 * TILES);

    bf16x8 w1b0 = *reinterpret_cast<const bf16x8*>(&W1T[(wv * 16 + l15) * 64 + g * 8]);
    bf16x8 w1b1 = *reinterpret_cast<const bf16x8*>(&W1T[(wv * 16 + l15) * 64 + 32 + g * 8]);
    bf16x8 w2b0[4], w2b1[4];
    #pragma unroll
    for (int ii = 0; ii < 4; ++ii) {
        int nt = wv * 4 + ii;
        w2b0[ii] = *reinterpret_cast<const bf16x8*>(&W2T[(nt * 16 + l15) * 64 + g * 8]);
        w2b1[ii] = *reinterpret_cast<const bf16x8*>(&W2T[(nt * 16 + l15) * 64 + 32 + g * 8]);
    }

    if (tid < 32 * TILES) {
        int p = p0 + tid;
        eid_s[tid] = order[p];
        src_s[tid] = src_srt[p];
        dst_s[tid] = dst_srt[p];
        *reinterpret_cast<f32x4*>(&sh_s[tid][0]) =
            *reinterpret_cast<const f32x4*>(&sh_srt[(size_t)p * 4]);
    }
    __syncthreads();

    const int tid2 = tid & 127;
    int region, cb, iv;
    if (tid2 < 48)       { region = 0; cb = tid2 & 15;        iv = tid2 >> 4; }
    else if (tid2 < 64)  { region = 1; cb = tid2 - 48;        iv = 0; }
    else if (tid2 < 88)  { region = 2; cb = (tid2 - 64) & 7;  iv = (tid2 - 64) >> 3; }
    else if (tid2 < 112) { region = 3; cb = (tid2 - 88) & 7;  iv = (tid2 - 88) >> 3; }
    else if (tid2 < 120) { region = 4; cb = tid2 - 112;       iv = 0; }
    else                 { region = 5; cb = 0; iv = 0; }
    int rbase = 0, woff = 0, doff = 0;
    if (region == 0)      { rbase = 96 + iv * 64 + 4 * cb;  woff = 64 + 4 * cb;  doff = 4 * cb; }
    else if (region == 1) { rbase = 4 * cb;                 woff = 4 * cb;       doff = 4 * cb; }
    else if (region == 2) { rbase = 288 + iv * 32 + 4 * cb; woff = 128 + 4 * cb; doff = 64 + iv * 32 + 4 * cb; }
    else if (region == 3) { rbase = 384 + iv * 32 + 4 * cb; woff = 192 + 4 * cb; }
    else if (region == 4) { rbase = 64 + 4 * cb;            woff = 160 + 4 * cb; }
    int i1 = iv + 1; if (i1 == 3) i1 = 0;
    int i2 = 3 - iv - i1;

    f32x4 acc = {0.f, 0.f, 0.f, 0.f};
    int cur = src_s[(tid >> 7) * 16];

    f32x4 efr[2];
    auto load_ef = [&](int t) {
        int ebase = t * 32;
        #pragma unroll
        for (int r = 0; r < 2; ++r) {
            int q = tid + r * 256;
            int el = q >> 4, qf = q & 15;
            efr[r] = *reinterpret_cast<const f32x4*>(
                edge_feature + (size_t)eid_s[ebase + el] * 64 + qf * 4);
        }
    };
    auto write_ef = [&]() {
        #pragma unroll
        for (int r = 0; r < 2; ++r) {
            int q = tid + r * 256;
            int el = q >> 4, f0 = (q & 15) * 4;
            b16x4 h;
            #pragma unroll
            for (int j = 0; j < 4; ++j) h[j] = (short)f2b(efr[r][j]);
            *reinterpret_cast<b16x4*>(&A1[el * 64 + (f0 ^ ((el & 7) << 3))]) = h;
        }
    };
    auto issue_df = [&](int t, int b) {
        int ebase = t * 32;
        #pragma unroll
        for (int r = 0; r < 3; ++r) {
            int idx = tid + r * 256;
            if (idx < 640) {
                int el = idx / 20, off = idx - el * 20;
                gl_lds16(st_vt16 + (size_t)dst_s[ebase + el] * 160 + off * 8,
                         &df[b][idx * 8]);
            }
        }
    };

    issue_df(0, 0);
    load_ef(0);

    for (int t = 0; t < TILES; ++t) {
        const int b = t & 1;
        write_ef();
        __syncthreads();
        if (t < TILES - 1) {
            issue_df(t + 1, b ^ 1);
            load_ef(t + 1);
        }
        {
            const int nt = wv;
            #pragma unroll
            for (int mt = 0; mt < 2; ++mt) {
                f32x4 c4 = {0.f, 0.f, 0.f, 0.f};
                int ra = mt * 16 + l15;
                int sw = (ra & 7) << 3;
                bf16x8 a0 = *reinterpret_cast<const bf16x8*>(&A1[ra * 64 + ((g * 8) ^ sw)]);
                bf16x8 a1 = *reinterpret_cast<const bf16x8*>(&A1[ra * 64 + ((32 + g * 8) ^ sw)]);
                c4 = __builtin_amdgcn_mfma_f32_16x16x32_bf16(a0, w1b0, c4, 0, 0, 0);
                c4 = __builtin_amdgcn_mfma_f32_16x16x32_bf16(a1, w1b1, c4, 0, 0, 0);
                #pragma unroll
                for (int r = 0; r < 4; ++r) {
                    int row = mt * 16 + g * 4 + r;
                    int col = nt * 16 + l15;
                    Hs[row * 64 + (col ^ ((row & 7) << 3))] = f2b(fmaxf(c4[r], 0.f));
                }
            }
        }
        __syncthreads();
        {
            #pragma unroll
            for (int ii = 0; ii < 4; ++ii) {
                int nt = wv * 4 + ii;
                #pragma unroll
                for (int mt = 0; mt < 2; ++mt) {
                    f32x4 c4 = {0.f, 0.f, 0.f, 0.f};
                    int ra = mt * 16 + l15;
                    int sw = (ra & 7) << 3;
                    bf16x8 a0 = *reinterpret_cast<const bf16x8*>(&Hs[ra * 64 + ((g * 8) ^ sw)]);
                    bf16x8 a1 = *reinterpret_cast<const bf16x8*>(&Hs[ra * 64 + ((32 + g * 8) ^ sw)]);
                    c4 = __builtin_amdgcn_mfma_f32_16x16x32_bf16(a0, w2b0[ii], c4, 0, 0, 0);
                    c4 = __builtin_amdgcn_mfma_f32_16x16x32_bf16(a1, w2b1[ii], c4, 0, 0, 0);
                    if (nt < 14) {
                        #pragma unroll
                        for (int r = 0; r < 4; ++r) {
                            int row = mt * 16 + g * 4 + r;
                            w_s[row * 224 + nt * 16 + l15] = f2b(c4[r]);
                        }
                    }
                }
            }
        }
        __syncthreads();
        if (region < 5) {
            const int e0l = (tid >> 7) * 16;
            #pragma unroll 4
            for (int j2 = 0; j2 < 16; ++j2) {
                int el = e0l + j2;
                int eg = t * 32 + el;
                int s = src_s[eg];
                if (s != cur) {
                    #pragma unroll
                    for (int j = 0; j < 4; ++j)
                        atomicAdd(&agg[(size_t)cur * 480 + rbase + j], acc[j]);
                    acc = (f32x4){0.f, 0.f, 0.f, 0.f};
                    cur = s;
                }
                const unsigned short* dfp = &df[b][el * 160];
                const unsigned short* we  = &w_s[el * 224];
                b16x4 w = *reinterpret_cast<const b16x4*>(we + woff);
                if (region == 0) {
                    b16x4 x = *reinterpret_cast<const b16x4*>(dfp + doff);
                    float sh = sh_s[eg][iv];
                    #pragma unroll
                    for (int j = 0; j < 4; ++j)
                        acc[j] += b2f((unsigned short)w[j]) * b2f((unsigned short)x[j]) * sh;
                } else if (region == 1 || region == 2) {
                    b16x4 x = *reinterpret_cast<const b16x4*>(dfp + doff);
                    #pragma unroll
                    for (int j = 0; j < 4; ++j)
                        acc[j] += b2f((unsigned short)w[j]) * b2f((unsigned short)x[j]);
                } else if (region == 3) {
                    b16x4 xA = *reinterpret_cast<const b16x4*>(dfp + 64 + i1 * 32 + 4 * cb);
                    b16x4 xB = *reinterpret_cast<const b16x4*>(dfp + 64 + i2 * 32 + 4 * cb);
                    float shA = sh_s[eg][i1], shB = sh_s[eg][i2];
                    #pragma unroll
                    for (int j = 0; j < 4; ++j)
                        acc[j] += b2f((unsigned short)w[j]) *
                                  (b2f((unsigned short)xA[j]) * shB -
                                   b2f((unsigned short)xB[j]) * shA) * INV_SQRT2F;
                } else {
                    b16x4 x0 = *reinterpret_cast<const b16x4*>(dfp + 64 + 4 * cb);
                    b16x4 x1 = *reinterpret_cast<const b16x4*>(dfp + 96 + 4 * cb);
                    b16x4 x2 = *reinterpret_cast<const b16x4*>(dfp + 128 + 4 * cb);
                    float s0 = sh_s[eg][0], s1 = sh_s[eg][1], s2 = sh_s[eg][2];
                    #pragma unroll
                    for (int j = 0; j < 4; ++j)
                        acc[j] += b2f((unsigned short)w[j]) *
                                  (b2f((unsigned short)x0[j]) * s0 +
                                   b2f((unsigned short)x1[j]) * s1 +
                                   b2f((unsigned short)x2[j]) * s2) * INV_SQRT3F;
                }
            }
        }
    }
    if (region < 5) {
        #pragma unroll
        for (int j = 0; j < 4; ++j)
            atomicAdd(&agg[(size_t)cur * 480 + rbase + j], acc[j]);
    }
}

// ---------------------------------------------------------------------------
// Kernel 3: per-node output transform + gating (reads permuted agg layout).
// ---------------------------------------------------------------------------
__global__ __launch_bounds__(128) void out_kernel(
    const float* __restrict__ agg,
    const float* __restrict__ nf,
    const float* __restrict__ Wskip0,
    const float* __restrict__ Wskip1,
    const float* __restrict__ Wout_s,
    const float* __restrict__ Wout_v,
    float* __restrict__ out)
{
    __shared__ float aggl[480];
    __shared__ float os_s[96];
    const int n = blockIdx.x;
    const int tid = threadIdx.x;
    const float* nfn = nf + (size_t)n * 160;

    for (int idx = tid; idx < 480; idx += 128)
        aggl[idx] = agg[(size_t)n * 480 + idx] * (1.f / 32.f);
    __syncthreads();

    if (tid < 96) {
        float acc = 0.f;
        #pragma unroll 8
        for (int k = 0; k < 64; ++k) acc += nfn[k] * Wskip0[k * 96 + tid];
        for (int r = 0; r < 96; ++r) acc += aggl[r] * Wout_s[r * 96 + tid];
        os_s[tid] = acc;
    }
    __syncthreads();

    if (tid < 64) {
        float x = os_s[tid];
        out[(size_t)n * 160 + tid] = x / (1.f + expf(-x));  // silu
    }
    if (tid < 96) {
        int t = tid;
        int k = t / 3, i = t - 3 * k;
        float acc = 0.f;
        #pragma unroll 8
        for (int m = 0; m < 32; ++m) acc += nfn[64 + m * 3 + i] * Wskip1[m * 32 + k];
        #pragma unroll 8
        for (int m = 0; m < 64; ++m) acc += aggl[96 + i * 64 + m] * Wout_v[m * 32 + k];
        #pragma unroll 8
        for (int m = 0; m < 32; ++m) acc += aggl[288 + i * 32 + m] * Wout_v[(64 + m) * 32 + k];
        #pragma unroll 8
        for (int m = 0; m < 32; ++m) acc += aggl[384 + i * 32 + m] * Wout_v[(96 + m) * 32 + k];
        float g = os_s[64 + k];
        g = 1.f / (1.f + expf(-g));  // sigmoid gate
        out[(size_t)n * 160 + 64 + t] = g * acc;
    }
}

// ---------------------------------------------------------------------------
extern "C" void kernel_launch(void* const* d_in, const int* in_sizes, int n_in,
                              void* d_out, int out_size, void* d_ws, size_t ws_size,
                              hipStream_t stream)
{
    const float* nf     = (const float*)d_in[0];
    const float* ea     = (const float*)d_in[1];
    const float* ef     = (const float*)d_in[2];
    const float* Wskip0 = (const float*)d_in[3];
    const float* Wskip1 = (const float*)d_in[4];
    const float* Wnl0   = (const float*)d_in[5];
    const float* Wnl1   = (const float*)d_in[6];
    const float* Wfc1   = (const float*)d_in[7];
    const float* Wfc2   = (const float*)d_in[8];
    const float* Wout_s = (const float*)d_in[9];
    const float* Wout_v = (const float*)d_in[10];
    const int*   eidx   = (const int*)d_in[11];
    float* out = (float*)d_out;

    // workspace layout (16B-aligned sections)
    int*   cnt       = (int*)d_ws;                        // 10000
    int*   fill      = cnt + 10000;                       // 10000
    int*   row_start = fill + 10000;                      // 10004
    int*   order     = row_start + 10004;                 // 320000
    int*   src_srt   = order + 320000;                    // 320000
    int*   dst_srt   = src_srt + 320000;                  // 320000
    float* sh_srt    = (float*)(dst_srt + 320000);        // 1,280,000
    float* agg       = sh_srt + 1280000;                  // 4,800,000
    unsigned short* st_vt16 = (unsigned short*)(agg + 4800000); // 1,600,000
    unsigned short* W1T = st_vt16 + 1600000;              // 4,096
    unsigned short* W2T = W1T + 4096;                     // 16,384 (256 rows, 224 valid)
    unsigned short* w_srt = W2T + 16384;                  // 71,680,000 (split path only)

    const size_t need_split =
        (size_t)((const char*)(w_srt + (size_t)N_EDGES * 224) - (const char*)d_ws);
    const bool use_split = (ws_size >= need_split);

    hipMemsetAsync(cnt, 0, 20000 * sizeof(int), stream);               // cnt+fill
    hipMemsetAsync(agg, 0, (size_t)N_NODES * 480 * sizeof(float), stream);

    prep_kernel<<<7572, 256, 0, stream>>>(
        nf, Wnl0, Wnl1, Wfc1, Wfc2, eidx, st_vt16, W1T, W2T, cnt);

    scan_kernel<<<1, 1024, 0, stream>>>(cnt, row_start);
    scatter_kernel<<<(N_EDGES + 255) / 256, 256, 0, stream>>>(
        eidx, ea, row_start, fill, order, src_srt, dst_srt, sh_srt);

    if (use_split) {
        edge_mlp<<<NBLK, 256, 0, stream>>>(W1T, W2T, order, ef, w_srt);
        edge_msg<<<NBLK, 256, 0, stream>>>(src_srt, dst_srt, sh_srt,
                                           w_srt, st_vt16, agg);
    } else {
        edge_conv_fused<<<NBLK, 256, 0, stream>>>(
            W1T, W2T, order, src_srt, dst_srt, sh_srt, ef, st_vt16, agg);
    }

    out_kernel<<<N_NODES, 128, 0, stream>>>(
        agg, nf, Wskip0, Wskip1, Wout_s, Wout_v, out);
}

// Round 9
// 297.986 us; speedup vs baseline: 1.6565x; 1.3752x over previous
//
#include <hip/hip_runtime.h>
#include <math.h>

#define N_NODES 10000
#define N_EDGES 320000
#define TILES 5                 // edge_mlp: 5 tiles x 32 edges per block
#define NBLK (N_EDGES / (32 * TILES))   // 2000 blocks

#define SQRT3F     1.7320508075688772f
#define INV_SQRT3F 0.5773502691896258f
#define INV_SQRT2F 0.7071067811865476f

typedef short bf16x8 __attribute__((ext_vector_type(8)));
typedef short b16x4  __attribute__((ext_vector_type(4)));
typedef float f32x4  __attribute__((ext_vector_type(4)));
typedef unsigned int u32;

static __device__ __forceinline__ unsigned short f2b(float f) {
    unsigned int u = __float_as_uint(f);
    unsigned int r = (u + 0x7fffu + ((u >> 16) & 1u)) >> 16;   // RNE
    return (unsigned short)r;
}
static __device__ __forceinline__ float b2f(unsigned short h) {
    return __uint_as_float(((unsigned int)h) << 16);
}

// direct global->LDS 16B copy (lane-linear dest: base + lane*16)
static __device__ __forceinline__ void gl_lds16(const void* g, void* l) {
    __builtin_amdgcn_global_load_lds(
        (const __attribute__((address_space(1))) u32*)g,
        (__attribute__((address_space(3))) u32*)l,
        16, 0, 0);
}

// ---------------------------------------------------------------------------
// Kernel P: merged prep — node transforms (blocks 0..6249), src histogram
// (6250..7499), weight conversion (7500..7571).
//   st_vt16[n][160] bf16: [0..63] s_t = nf_s @ W_nl0
//                         [64..159] v_t TRANSPOSED layout i*32+k
// ---------------------------------------------------------------------------
__global__ __launch_bounds__(256) void prep_kernel(
    const float* __restrict__ nf,
    const float* __restrict__ Wnl0,
    const float* __restrict__ Wnl1,
    const float* __restrict__ Wfc1,
    const float* __restrict__ Wfc2,
    const int* __restrict__ eidx,
    unsigned short* __restrict__ st_vt16,
    unsigned short* __restrict__ W1T,
    unsigned short* __restrict__ W2T,
    int* __restrict__ cnt)
{
    const int b = blockIdx.x;
    const int tid = threadIdx.x;
    if (b < 6250) {
        int gid = b * 256 + tid;
        if (gid >= N_NODES * 160) return;
        int n = gid / 160;
        int j = gid - n * 160;
        const float* nfn = nf + (size_t)n * 160;
        float acc = 0.f;
        if (j < 64) {
            #pragma unroll 8
            for (int k = 0; k < 64; ++k) acc += nfn[k] * Wnl0[k * 64 + j];
        } else {
            int t = j - 64;
            int i = t >> 5, k = t & 31;
            #pragma unroll 8
            for (int m = 0; m < 32; ++m) acc += nfn[64 + m * 3 + i] * Wnl1[m * 32 + k];
        }
        st_vt16[(size_t)n * 160 + j] = f2b(acc);
    } else if (b < 7500) {
        int e = (b - 6250) * 256 + tid;
        if (e < N_EDGES) atomicAdd(&cnt[eidx[e]], 1);
    } else {
        int idx = (b - 7500) * 256 + tid;
        if (idx < 4096) {
            int n = idx >> 6, k = idx & 63;
            W1T[idx] = f2b(Wfc1[k * 64 + n]);
        } else if (idx < 18432) {
            int j = idx - 4096;
            int n = j >> 6, k = j & 63;
            W2T[j] = f2b(Wfc2[k * 224 + n]);
        }
    }
}

// ---------------------------------------------------------------------------
// scan + scatter (sorting by src)
// ---------------------------------------------------------------------------
__global__ __launch_bounds__(1024) void scan_kernel(
    const int* __restrict__ cnt, int* __restrict__ row_start)
{
    __shared__ int part[1024];
    const int t = threadIdx.x;
    const int CH = 10;
    int base = t * CH;
    int s = 0;
    for (int i = 0; i < CH; ++i) {
        int idx = base + i;
        if (idx < N_NODES) s += cnt[idx];
    }
    part[t] = s;
    __syncthreads();
    for (int off = 1; off < 1024; off <<= 1) {
        int v = (t >= off) ? part[t - off] : 0;
        __syncthreads();
        part[t] += v;
        __syncthreads();
    }
    int run = (t == 0) ? 0 : part[t - 1];
    for (int i = 0; i < CH; ++i) {
        int idx = base + i;
        if (idx < N_NODES) { row_start[idx] = run; run += cnt[idx]; }
    }
    if (t == 1023) row_start[N_NODES] = run;
}

__global__ __launch_bounds__(256) void scatter_kernel(
    const int* __restrict__ eidx, const float* __restrict__ edge_attr,
    const int* __restrict__ row_start,
    int* __restrict__ fill, int* __restrict__ order,
    int* __restrict__ src_srt, int* __restrict__ dst_srt,
    float* __restrict__ sh_srt)
{
    int e = blockIdx.x * 256 + threadIdx.x;
    if (e >= N_EDGES) return;
    int s = eidx[e];
    int p = atomicAdd(&fill[s], 1) + row_start[s];
    order[p] = e;
    src_srt[p] = s;
    dst_srt[p] = eidx[N_EDGES + e];
    float x = edge_attr[(size_t)e * 3 + 0];
    float y = edge_attr[(size_t)e * 3 + 1];
    float z = edge_attr[(size_t)e * 3 + 2];
    float inv = SQRT3F / sqrtf(x * x + y * y + z * z);
    sh_srt[(size_t)p * 4 + 0] = x * inv;
    sh_srt[(size_t)p * 4 + 1] = y * inv;
    sh_srt[(size_t)p * 4 + 2] = z * inv;
    sh_srt[(size_t)p * 4 + 3] = 0.f;
}

// ---------------------------------------------------------------------------
// Kernel A: pure MFMA MLP pipeline. Writes w_srt[p][224] bf16 coalesced.
// ---------------------------------------------------------------------------
__global__ __launch_bounds__(256, 5) void edge_mlp(
    const unsigned short* __restrict__ W1T,
    const unsigned short* __restrict__ W2T,
    const int* __restrict__ order,
    const float* __restrict__ edge_feature,
    unsigned short* __restrict__ w_srt)
{
    __shared__ __align__(16) unsigned short A1[32 * 64];      // 4 KB (swizzled)
    __shared__ __align__(16) unsigned short Hs[32 * 64];      // 4 KB (swizzled)
    __shared__ __align__(16) unsigned short w_s[32 * 224];    // 14 KB
    __shared__ int eid_s[160];

    const int tid  = threadIdx.x;
    const int lane = tid & 63;
    const int wv   = tid >> 6;
    const int l15  = lane & 15;
    const int g    = lane >> 4;
    const int p0   = blockIdx.x * (32 * TILES);

    bf16x8 w1b0 = *reinterpret_cast<const bf16x8*>(&W1T[(wv * 16 + l15) * 64 + g * 8]);
    bf16x8 w1b1 = *reinterpret_cast<const bf16x8*>(&W1T[(wv * 16 + l15) * 64 + 32 + g * 8]);
    bf16x8 w2b0[4], w2b1[4];
    #pragma unroll
    for (int ii = 0; ii < 4; ++ii) {
        int nt = wv * 4 + ii;
        w2b0[ii] = *reinterpret_cast<const bf16x8*>(&W2T[(nt * 16 + l15) * 64 + g * 8]);
        w2b1[ii] = *reinterpret_cast<const bf16x8*>(&W2T[(nt * 16 + l15) * 64 + 32 + g * 8]);
    }

    if (tid < 32 * TILES) eid_s[tid] = order[p0 + tid];
    __syncthreads();

    f32x4 efr[2];
    auto load_ef = [&](int t) {
        int ebase = t * 32;
        #pragma unroll
        for (int r = 0; r < 2; ++r) {
            int q = tid + r * 256;
            int el = q >> 4, qf = q & 15;
            efr[r] = *reinterpret_cast<const f32x4*>(
                edge_feature + (size_t)eid_s[ebase + el] * 64 + qf * 4);
        }
    };
    auto write_ef = [&]() {
        #pragma unroll
        for (int r = 0; r < 2; ++r) {
            int q = tid + r * 256;
            int el = q >> 4, f0 = (q & 15) * 4;
            b16x4 h;
            #pragma unroll
            for (int j = 0; j < 4; ++j) h[j] = (short)f2b(efr[r][j]);
            *reinterpret_cast<b16x4*>(&A1[el * 64 + (f0 ^ ((el & 7) << 3))]) = h;
        }
    };

    load_ef(0);

    for (int t = 0; t < TILES; ++t) {
        write_ef();
        __syncthreads();
        if (t < TILES - 1) load_ef(t + 1);

        // GEMM1: Hs = relu(A1 @ Wfc1)
        {
            const int nt = wv;
            #pragma unroll
            for (int mt = 0; mt < 2; ++mt) {
                f32x4 c4 = {0.f, 0.f, 0.f, 0.f};
                int ra = mt * 16 + l15;
                int sw = (ra & 7) << 3;
                bf16x8 a0 = *reinterpret_cast<const bf16x8*>(&A1[ra * 64 + ((g * 8) ^ sw)]);
                bf16x8 a1 = *reinterpret_cast<const bf16x8*>(&A1[ra * 64 + ((32 + g * 8) ^ sw)]);
                c4 = __builtin_amdgcn_mfma_f32_16x16x32_bf16(a0, w1b0, c4, 0, 0, 0);
                c4 = __builtin_amdgcn_mfma_f32_16x16x32_bf16(a1, w1b1, c4, 0, 0, 0);
                #pragma unroll
                for (int r = 0; r < 4; ++r) {
                    int row = mt * 16 + g * 4 + r;
                    int col = nt * 16 + l15;
                    Hs[row * 64 + (col ^ ((row & 7) << 3))] = f2b(fmaxf(c4[r], 0.f));
                }
            }
        }
        __syncthreads();

        // GEMM2: w_s = Hs @ Wfc2 (stores masked nt<14)
        {
            #pragma unroll
            for (int ii = 0; ii < 4; ++ii) {
                int nt = wv * 4 + ii;
                #pragma unroll
                for (int mt = 0; mt < 2; ++mt) {
                    f32x4 c4 = {0.f, 0.f, 0.f, 0.f};
                    int ra = mt * 16 + l15;
                    int sw = (ra & 7) << 3;
                    bf16x8 a0 = *reinterpret_cast<const bf16x8*>(&Hs[ra * 64 + ((g * 8) ^ sw)]);
                    bf16x8 a1 = *reinterpret_cast<const bf16x8*>(&Hs[ra * 64 + ((32 + g * 8) ^ sw)]);
                    c4 = __builtin_amdgcn_mfma_f32_16x16x32_bf16(a0, w2b0[ii], c4, 0, 0, 0);
                    c4 = __builtin_amdgcn_mfma_f32_16x16x32_bf16(a1, w2b1[ii], c4, 0, 0, 0);
                    if (nt < 14) {
                        #pragma unroll
                        for (int r = 0; r < 4; ++r) {
                            int row = mt * 16 + g * 4 + r;
                            w_s[row * 224 + nt * 16 + l15] = f2b(c4[r]);
                        }
                    }
                }
            }
        }
        __syncthreads();

        // coalesced copy-out: 32x224 u16 = 896 x 16B
        {
            const size_t gbase = (size_t)(p0 + t * 32) * 224;
            for (int idx = tid; idx < 896; idx += 256) {
                *reinterpret_cast<f32x4*>(&w_srt[gbase + idx * 8]) =
                    *reinterpret_cast<const f32x4*>(&w_s[idx * 8]);
            }
        }
    }
}

// ---------------------------------------------------------------------------
// Kernel B: per-NODE messages. One block per node; edges [row_start[n],
// row_start[n+1]) are contiguous (sorted). Zero global atomics: accumulate in
// registers, combine halves in LDS, apply W_out + skips + gating in-block,
// write final out[n][160]. w + df staged via global_load_lds per 32-edge chunk.
// ---------------------------------------------------------------------------
__global__ __launch_bounds__(256, 5) void node_msg(
    const int* __restrict__ row_start,
    const int* __restrict__ dst_srt,
    const float* __restrict__ sh_srt,
    const unsigned short* __restrict__ w_srt,
    const unsigned short* __restrict__ st_vt16,
    const float* __restrict__ nf,
    const float* __restrict__ Wskip0,
    const float* __restrict__ Wskip1,
    const float* __restrict__ Wout_s,
    const float* __restrict__ Wout_v,
    float* __restrict__ out)
{
    __shared__ __align__(16) unsigned short w_l[32 * 224];  // 14336 B
    __shared__ __align__(16) unsigned short df[32 * 160];   // 10240 B
    __shared__ float aggbuf[480];
    __shared__ float os_s[96];
    __shared__ float sh_c[32][4];
    __shared__ int   dst_c[32];

    // chunked XCD remap (10000 = 8 * 1250): neighbor nodes share an XCD L2
    const int n   = (blockIdx.x & 7) * 1250 + (blockIdx.x >> 3);
    const int tid = threadIdx.x;
    const int p_start = row_start[n];
    const int p_end   = row_start[n + 1];

    // region setup (fixed per thread); halves tid<128 / tid>=128 split edges
    const int tid2 = tid & 127;
    const int half = tid >> 7;
    int region, cb, iv;
    if (tid2 < 48)       { region = 0; cb = tid2 & 15;        iv = tid2 >> 4; }
    else if (tid2 < 64)  { region = 1; cb = tid2 - 48;        iv = 0; }
    else if (tid2 < 88)  { region = 2; cb = (tid2 - 64) & 7;  iv = (tid2 - 64) >> 3; }
    else if (tid2 < 112) { region = 3; cb = (tid2 - 88) & 7;  iv = (tid2 - 88) >> 3; }
    else if (tid2 < 120) { region = 4; cb = tid2 - 112;       iv = 0; }
    else                 { region = 5; cb = 0; iv = 0; }
    int rbase = 0, woff = 0, doff = 0;
    if (region == 0)      { rbase = 96 + iv * 64 + 4 * cb;  woff = 64 + 4 * cb;  doff = 4 * cb; }
    else if (region == 1) { rbase = 4 * cb;                 woff = 4 * cb;       doff = 4 * cb; }
    else if (region == 2) { rbase = 288 + iv * 32 + 4 * cb; woff = 128 + 4 * cb; doff = 64 + iv * 32 + 4 * cb; }
    else if (region == 3) { rbase = 384 + iv * 32 + 4 * cb; woff = 192 + 4 * cb; }
    else if (region == 4) { rbase = 64 + 4 * cb;            woff = 160 + 4 * cb; }
    int i1 = iv + 1; if (i1 == 3) i1 = 0;
    int i2 = 3 - iv - i1;

    f32x4 acc = {0.f, 0.f, 0.f, 0.f};

    for (int pb = p_start; pb < p_end; pb += 32) {
        __syncthreads();                       // prev chunk's compute done
        if (tid < 32) {
            int pp = min(pb + tid, p_end - 1);
            dst_c[tid] = dst_srt[pp];
            *reinterpret_cast<f32x4*>(&sh_c[tid][0]) =
                *reinterpret_cast<const f32x4*>(&sh_srt[(size_t)pp * 4]);
        }
        __syncthreads();

        // stage df (640 x 16B) + w (896 x 16B, contiguous rows)
        #pragma unroll
        for (int r = 0; r < 3; ++r) {
            int idx = tid + r * 256;
            if (idx < 640) {                   // wave-uniform on/off
                int el = idx / 20, off = idx - el * 20;
                gl_lds16(st_vt16 + (size_t)dst_c[el] * 160 + off * 8, &df[idx * 8]);
            }
        }
        #pragma unroll
        for (int r = 0; r < 4; ++r) {
            int idx = tid + r * 256;
            if (idx < 896) {                   // wave-uniform on/off
                gl_lds16(w_srt + (size_t)pb * 224 + idx * 8, &w_l[idx * 8]);
            }
        }
        __syncthreads();                       // vmcnt drained: df + w ready

        const int nvalid = p_end - pb;
        if (region < 5) {
            const int e0l = half * 16;
            #pragma unroll 4
            for (int j2 = 0; j2 < 16; ++j2) {
                int el = e0l + j2;
                if (el >= nvalid) break;       // uniform per half-wave
                const unsigned short* dfp = &df[el * 160];
                const unsigned short* we  = &w_l[el * 224];
                b16x4 w = *reinterpret_cast<const b16x4*>(we + woff);
                if (region == 0) {
                    b16x4 x = *reinterpret_cast<const b16x4*>(dfp + doff);
                    float sh = sh_c[el][iv];
                    #pragma unroll
                    for (int j = 0; j < 4; ++j)
                        acc[j] += b2f((unsigned short)w[j]) * b2f((unsigned short)x[j]) * sh;
                } else if (region == 1 || region == 2) {
                    b16x4 x = *reinterpret_cast<const b16x4*>(dfp + doff);
                    #pragma unroll
                    for (int j = 0; j < 4; ++j)
                        acc[j] += b2f((unsigned short)w[j]) * b2f((unsigned short)x[j]);
                } else if (region == 3) {
                    b16x4 xA = *reinterpret_cast<const b16x4*>(dfp + 64 + i1 * 32 + 4 * cb);
                    b16x4 xB = *reinterpret_cast<const b16x4*>(dfp + 64 + i2 * 32 + 4 * cb);
                    float shA = sh_c[el][i1], shB = sh_c[el][i2];
                    #pragma unroll
                    for (int j = 0; j < 4; ++j)
                        acc[j] += b2f((unsigned short)w[j]) *
                                  (b2f((unsigned short)xA[j]) * shB -
                                   b2f((unsigned short)xB[j]) * shA) * INV_SQRT2F;
                } else {
                    b16x4 x0 = *reinterpret_cast<const b16x4*>(dfp + 64 + 4 * cb);
                    b16x4 x1 = *reinterpret_cast<const b16x4*>(dfp + 96 + 4 * cb);
                    b16x4 x2 = *reinterpret_cast<const b16x4*>(dfp + 128 + 4 * cb);
                    float s0 = sh_c[el][0], s1 = sh_c[el][1], s2 = sh_c[el][2];
                    #pragma unroll
                    for (int j = 0; j < 4; ++j)
                        acc[j] += b2f((unsigned short)w[j]) *
                                  (b2f((unsigned short)x0[j]) * s0 +
                                   b2f((unsigned short)x1[j]) * s1 +
                                   b2f((unsigned short)x2[j]) * s2) * INV_SQRT3F;
                }
            }
        }
    }

    // combine halves into aggbuf (half0 writes all 480, half1 adds)
    __syncthreads();
    if (half == 0 && region < 5) {
        #pragma unroll
        for (int j = 0; j < 4; ++j) aggbuf[rbase + j] = acc[j];
    }
    __syncthreads();
    if (half == 1 && region < 5) {
        #pragma unroll
        for (int j = 0; j < 4; ++j) aggbuf[rbase + j] += acc[j];
    }
    __syncthreads();

    // fused output transform + gating (agg scaled by 1/32; skips unscaled)
    const float* nfn = nf + (size_t)n * 160;
    if (tid < 96) {
        float sk = 0.f;
        #pragma unroll 8
        for (int k = 0; k < 64; ++k) sk += nfn[k] * Wskip0[k * 96 + tid];
        float a = 0.f;
        for (int r = 0; r < 96; ++r) a += aggbuf[r] * Wout_s[r * 96 + tid];
        os_s[tid] = a * (1.f / 32.f) + sk;
    }
    __syncthreads();

    if (tid < 64) {
        float x = os_s[tid];
        out[(size_t)n * 160 + tid] = x / (1.f + expf(-x));  // silu
    }
    if (tid < 96) {
        int t = tid;
        int k = t / 3, i = t - 3 * k;
        float sk = 0.f;
        #pragma unroll 8
        for (int m = 0; m < 32; ++m) sk += nfn[64 + m * 3 + i] * Wskip1[m * 32 + k];
        float a = 0.f;
        #pragma unroll 8
        for (int m = 0; m < 64; ++m) a += aggbuf[96 + i * 64 + m] * Wout_v[m * 32 + k];
        #pragma unroll 8
        for (int m = 0; m < 32; ++m) a += aggbuf[288 + i * 32 + m] * Wout_v[(64 + m) * 32 + k];
        #pragma unroll 8
        for (int m = 0; m < 32; ++m) a += aggbuf[384 + i * 32 + m] * Wout_v[(96 + m) * 32 + k];
        float g = os_s[64 + k];
        g = 1.f / (1.f + expf(-g));  // sigmoid gate
        out[(size_t)n * 160 + 64 + t] = g * (a * (1.f / 32.f) + sk);
    }
}

// ---------------------------------------------------------------------------
// Fallback path (only if ws can't hold w_srt): round-6 fused kernel + out.
// ---------------------------------------------------------------------------
__global__ __launch_bounds__(256, 3) void edge_conv_fused(
    const unsigned short* __restrict__ W1T,
    const unsigned short* __restrict__ W2T,
    const int* __restrict__ order,
    const int* __restrict__ src_srt,
    const int* __restrict__ dst_srt,
    const float* __restrict__ sh_srt,
    const float* __restrict__ edge_feature,
    const unsigned short* __restrict__ st_vt16,
    float* __restrict__ agg)
{
    __shared__ __align__(16) unsigned short A1[32 * 64];
    __shared__ __align__(16) unsigned short Hs[32 * 64];
    __shared__ __align__(16) unsigned short w_s[32 * 224];
    __shared__ __align__(16) unsigned short df[2][32 * 160];
    __shared__ int   eid_s[160];
    __shared__ int   src_s[160];
    __shared__ int   dst_s[160];
    __shared__ float sh_s[160][4];

    const int tid  = threadIdx.x;
    const int lane = tid & 63;
    const int wv   = tid >> 6;
    const int l15  = lane & 15;
    const int g    = lane >> 4;
    const int p0   = blockIdx.x * (32 * TILES);

    bf16x8 w1b0 = *reinterpret_cast<const bf16x8*>(&W1T[(wv * 16 + l15) * 64 + g * 8]);
    bf16x8 w1b1 = *reinterpret_cast<const bf16x8*>(&W1T[(wv * 16 + l15) * 64 + 32 + g * 8]);
    bf16x8 w2b0[4], w2b1[4];
    #pragma unroll
    for (int ii = 0; ii < 4; ++ii) {
        int nt = wv * 4 + ii;
        w2b0[ii] = *reinterpret_cast<const bf16x8*>(&W2T[(nt * 16 + l15) * 64 + g * 8]);
        w2b1[ii] = *reinterpret_cast<const bf16x8*>(&W2T[(nt * 16 + l15) * 64 + 32 + g * 8]);
    }

    if (tid < 32 * TILES) {
        int p = p0 + tid;
        eid_s[tid] = order[p];
        src_s[tid] = src_srt[p];
        dst_s[tid] = dst_srt[p];
        *reinterpret_cast<f32x4*>(&sh_s[tid][0]) =
            *reinterpret_cast<const f32x4*>(&sh_srt[(size_t)p * 4]);
    }
    __syncthreads();

    const int tid2 = tid & 127;
    int region, cb, iv;
    if (tid2 < 48)       { region = 0; cb = tid2 & 15;        iv = tid2 >> 4; }
    else if (tid2 < 64)  { region = 1; cb = tid2 - 48;        iv = 0; }
    else if (tid2 < 88)  { region = 2; cb = (tid2 - 64) & 7;  iv = (tid2 - 64) >> 3; }
    else if (tid2 < 112) { region = 3; cb = (tid2 - 88) & 7;  iv = (tid2 - 88) >> 3; }
    else if (tid2 < 120) { region = 4; cb = tid2 - 112;       iv = 0; }
    else                 { region = 5; cb = 0; iv = 0; }
    int rbase = 0, woff = 0, doff = 0;
    if (region == 0)      { rbase = 96 + iv * 64 + 4 * cb;  woff = 64 + 4 * cb;  doff = 4 * cb; }
    else if (region == 1) { rbase = 4 * cb;                 woff = 4 * cb;       doff = 4 * cb; }
    else if (region == 2) { rbase = 288 + iv * 32 + 4 * cb; woff = 128 + 4 * cb; doff = 64 + iv * 32 + 4 * cb; }
    else if (region == 3) { rbase = 384 + iv * 32 + 4 * cb; woff = 192 + 4 * cb; }
    else if (region == 4) { rbase = 64 + 4 * cb;            woff = 160 + 4 * cb; }
    int i1 = iv + 1; if (i1 == 3) i1 = 0;
    int i2 = 3 - iv - i1;

    f32x4 acc = {0.f, 0.f, 0.f, 0.f};
    int cur = src_s[(tid >> 7) * 16];

    f32x4 efr[2];
    auto load_ef = [&](int t) {
        int ebase = t * 32;
        #pragma unroll
        for (int r = 0; r < 2; ++r) {
            int q = tid + r * 256;
            int el = q >> 4, qf = q & 15;
            efr[r] = *reinterpret_cast<const f32x4*>(
                edge_feature + (size_t)eid_s[ebase + el] * 64 + qf * 4);
        }
    };
    auto write_ef = [&]() {
        #pragma unroll
        for (int r = 0; r < 2; ++r) {
            int q = tid + r * 256;
            int el = q >> 4, f0 = (q & 15) * 4;
            b16x4 h;
            #pragma unroll
            for (int j = 0; j < 4; ++j) h[j] = (short)f2b(efr[r][j]);
            *reinterpret_cast<b16x4*>(&A1[el * 64 + (f0 ^ ((el & 7) << 3))]) = h;
        }
    };
    auto issue_df = [&](int t, int b) {
        int ebase = t * 32;
        #pragma unroll
        for (int r = 0; r < 3; ++r) {
            int idx = tid + r * 256;
            if (idx < 640) {
                int el = idx / 20, off = idx - el * 20;
                gl_lds16(st_vt16 + (size_t)dst_s[ebase + el] * 160 + off * 8,
                         &df[b][idx * 8]);
            }
        }
    };

    issue_df(0, 0);
    load_ef(0);

    for (int t = 0; t < TILES; ++t) {
        const int b = t & 1;
        write_ef();
        __syncthreads();
        if (t < TILES - 1) {
            issue_df(t + 1, b ^ 1);
            load_ef(t + 1);
        }
        {
            const int nt = wv;
            #pragma unroll
            for (int mt = 0; mt < 2; ++mt) {
                f32x4 c4 = {0.f, 0.f, 0.f, 0.f};
                int ra = mt * 16 + l15;
                int sw = (ra & 7) << 3;
                bf16x8 a0 = *reinterpret_cast<const bf16x8*>(&A1[ra * 64 + ((g * 8) ^ sw)]);
                bf16x8 a1 = *reinterpret_cast<const bf16x8*>(&A1[ra * 64 + ((32 + g * 8) ^ sw)]);
                c4 = __builtin_amdgcn_mfma_f32_16x16x32_bf16(a0, w1b0, c4, 0, 0, 0);
                c4 = __builtin_amdgcn_mfma_f32_16x16x32_bf16(a1, w1b1, c4, 0, 0, 0);
                #pragma unroll
                for (int r = 0; r < 4; ++r) {
                    int row = mt * 16 + g * 4 + r;
                    int col = nt * 16 + l15;
                    Hs[row * 64 + (col ^ ((row & 7) << 3))] = f2b(fmaxf(c4[r], 0.f));
                }
            }
        }
        __syncthreads();
        {
            #pragma unroll
            for (int ii = 0; ii < 4; ++ii) {
                int nt = wv * 4 + ii;
                #pragma unroll
                for (int mt = 0; mt < 2; ++mt) {
                    f32x4 c4 = {0.f, 0.f, 0.f, 0.f};
                    int ra = mt * 16 + l15;
                    int sw = (ra & 7) << 3;
                    bf16x8 a0 = *reinterpret_cast<const bf16x8*>(&Hs[ra * 64 + ((g * 8) ^ sw)]);
                    bf16x8 a1 = *reinterpret_cast<const bf16x8*>(&Hs[ra * 64 + ((32 + g * 8) ^ sw)]);
                    c4 = __builtin_amdgcn_mfma_f32_16x16x32_bf16(a0, w2b0[ii], c4, 0, 0, 0);
                    c4 = __builtin_amdgcn_mfma_f32_16x16x32_bf16(a1, w2b1[ii], c4, 0, 0, 0);
                    if (nt < 14) {
                        #pragma unroll
                        for (int r = 0; r < 4; ++r) {
                            int row = mt * 16 + g * 4 + r;
                            w_s[row * 224 + nt * 16 + l15] = f2b(c4[r]);
                        }
                    }
                }
            }
        }
        __syncthreads();
        if (region < 5) {
            const int e0l = (tid >> 7) * 16;
            #pragma unroll 4
            for (int j2 = 0; j2 < 16; ++j2) {
                int el = e0l + j2;
                int eg = t * 32 + el;
                int s = src_s[eg];
                if (s != cur) {
                    #pragma unroll
                    for (int j = 0; j < 4; ++j)
                        atomicAdd(&agg[(size_t)cur * 480 + rbase + j], acc[j]);
                    acc = (f32x4){0.f, 0.f, 0.f, 0.f};
                    cur = s;
                }
                const unsigned short* dfp = &df[b][el * 160];
                const unsigned short* we  = &w_s[el * 224];
                b16x4 w = *reinterpret_cast<const b16x4*>(we + woff);
                if (region == 0) {
                    b16x4 x = *reinterpret_cast<const b16x4*>(dfp + doff);
                    float sh = sh_s[eg][iv];
                    #pragma unroll
                    for (int j = 0; j < 4; ++j)
                        acc[j] += b2f((unsigned short)w[j]) * b2f((unsigned short)x[j]) * sh;
                } else if (region == 1 || region == 2) {
                    b16x4 x = *reinterpret_cast<const b16x4*>(dfp + doff);
                    #pragma unroll
                    for (int j = 0; j < 4; ++j)
                        acc[j] += b2f((unsigned short)w[j]) * b2f((unsigned short)x[j]);
                } else if (region == 3) {
                    b16x4 xA = *reinterpret_cast<const b16x4*>(dfp + 64 + i1 * 32 + 4 * cb);
                    b16x4 xB = *reinterpret_cast<const b16x4*>(dfp + 64 + i2 * 32 + 4 * cb);
                    float shA = sh_s[eg][i1], shB = sh_s[eg][i2];
                    #pragma unroll
                    for (int j = 0; j < 4; ++j)
                        acc[j] += b2f((unsigned short)w[j]) *
                                  (b2f((unsigned short)xA[j]) * shB -
                                   b2f((unsigned short)xB[j]) * shA) * INV_SQRT2F;
                } else {
                    b16x4 x0 = *reinterpret_cast<const b16x4*>(dfp + 64 + 4 * cb);
                    b16x4 x1 = *reinterpret_cast<const b16x4*>(dfp + 96 + 4 * cb);
                    b16x4 x2 = *reinterpret_cast<const b16x4*>(dfp + 128 + 4 * cb);
                    float s0 = sh_s[eg][0], s1 = sh_s[eg][1], s2 = sh_s[eg][2];
                    #pragma unroll
                    for (int j = 0; j < 4; ++j)
                        acc[j] += b2f((unsigned short)w[j]) *
                                  (b2f((unsigned short)x0[j]) * s0 +
                                   b2f((unsigned short)x1[j]) * s1 +
                                   b2f((unsigned short)x2[j]) * s2) * INV_SQRT3F;
                }
            }
        }
    }
    if (region < 5) {
        #pragma unroll
        for (int j = 0; j < 4; ++j)
            atomicAdd(&agg[(size_t)cur * 480 + rbase + j], acc[j]);
    }
}

__global__ __launch_bounds__(128) void out_kernel(
    const float* __restrict__ agg,
    const float* __restrict__ nf,
    const float* __restrict__ Wskip0,
    const float* __restrict__ Wskip1,
    const float* __restrict__ Wout_s,
    const float* __restrict__ Wout_v,
    float* __restrict__ out)
{
    __shared__ float aggl[480];
    __shared__ float os_s[96];
    const int n = blockIdx.x;
    const int tid = threadIdx.x;
    const float* nfn = nf + (size_t)n * 160;

    for (int idx = tid; idx < 480; idx += 128)
        aggl[idx] = agg[(size_t)n * 480 + idx] * (1.f / 32.f);
    __syncthreads();

    if (tid < 96) {
        float acc = 0.f;
        #pragma unroll 8
        for (int k = 0; k < 64; ++k) acc += nfn[k] * Wskip0[k * 96 + tid];
        for (int r = 0; r < 96; ++r) acc += aggl[r] * Wout_s[r * 96 + tid];
        os_s[tid] = acc;
    }
    __syncthreads();

    if (tid < 64) {
        float x = os_s[tid];
        out[(size_t)n * 160 + tid] = x / (1.f + expf(-x));
    }
    if (tid < 96) {
        int t = tid;
        int k = t / 3, i = t - 3 * k;
        float acc = 0.f;
        #pragma unroll 8
        for (int m = 0; m < 32; ++m) acc += nfn[64 + m * 3 + i] * Wskip1[m * 32 + k];
        #pragma unroll 8
        for (int m = 0; m < 64; ++m) acc += aggl[96 + i * 64 + m] * Wout_v[m * 32 + k];
        #pragma unroll 8
        for (int m = 0; m < 32; ++m) acc += aggl[288 + i * 32 + m] * Wout_v[(64 + m) * 32 + k];
        #pragma unroll 8
        for (int m = 0; m < 32; ++m) acc += aggl[384 + i * 32 + m] * Wout_v[(96 + m) * 32 + k];
        float g = os_s[64 + k];
        g = 1.f / (1.f + expf(-g));
        out[(size_t)n * 160 + 64 + t] = g * acc;
    }
}

// ---------------------------------------------------------------------------
extern "C" void kernel_launch(void* const* d_in, const int* in_sizes, int n_in,
                              void* d_out, int out_size, void* d_ws, size_t ws_size,
                              hipStream_t stream)
{
    const float* nf     = (const float*)d_in[0];
    const float* ea     = (const float*)d_in[1];
    const float* ef     = (const float*)d_in[2];
    const float* Wskip0 = (const float*)d_in[3];
    const float* Wskip1 = (const float*)d_in[4];
    const float* Wnl0   = (const float*)d_in[5];
    const float* Wnl1   = (const float*)d_in[6];
    const float* Wfc1   = (const float*)d_in[7];
    const float* Wfc2   = (const float*)d_in[8];
    const float* Wout_s = (const float*)d_in[9];
    const float* Wout_v = (const float*)d_in[10];
    const int*   eidx   = (const int*)d_in[11];
    float* out = (float*)d_out;

    // workspace layout (16B-aligned sections)
    int*   cnt       = (int*)d_ws;                        // 10000
    int*   fill      = cnt + 10000;                       // 10000
    int*   row_start = fill + 10000;                      // 10004
    int*   order     = row_start + 10004;                 // 320000
    int*   src_srt   = order + 320000;                    // 320000
    int*   dst_srt   = src_srt + 320000;                  // 320000
    float* sh_srt    = (float*)(dst_srt + 320000);        // 1,280,000
    float* agg       = sh_srt + 1280000;                  // 4,800,000 (fallback only)
    unsigned short* st_vt16 = (unsigned short*)(agg + 4800000); // 1,600,000
    unsigned short* W1T = st_vt16 + 1600000;              // 4,096
    unsigned short* W2T = W1T + 4096;                     // 16,384 (256 rows, 224 valid)
    unsigned short* w_srt = W2T + 16384;                  // (N_EDGES+32)*224 (split only)

    const size_t need_split =
        (size_t)((const char*)(w_srt + (size_t)(N_EDGES + 32) * 224) - (const char*)d_ws);
    const bool use_split = (ws_size >= need_split);

    hipMemsetAsync(cnt, 0, 20000 * sizeof(int), stream);   // cnt+fill

    prep_kernel<<<7572, 256, 0, stream>>>(
        nf, Wnl0, Wnl1, Wfc1, Wfc2, eidx, st_vt16, W1T, W2T, cnt);

    scan_kernel<<<1, 1024, 0, stream>>>(cnt, row_start);
    scatter_kernel<<<(N_EDGES + 255) / 256, 256, 0, stream>>>(
        eidx, ea, row_start, fill, order, src_srt, dst_srt, sh_srt);

    if (use_split) {
        edge_mlp<<<NBLK, 256, 0, stream>>>(W1T, W2T, order, ef, w_srt);
        node_msg<<<N_NODES, 256, 0, stream>>>(
            row_start, dst_srt, sh_srt, w_srt, st_vt16,
            nf, Wskip0, Wskip1, Wout_s, Wout_v, out);
    } else {
        hipMemsetAsync(agg, 0, (size_t)N_NODES * 480 * sizeof(float), stream);
        edge_conv_fused<<<NBLK, 256, 0, stream>>>(
            W1T, W2T, order, src_srt, dst_srt, sh_srt, ef, st_vt16, agg);
        out_kernel<<<N_NODES, 128, 0, stream>>>(
            agg, nf, Wskip0, Wskip1, Wout_s, Wout_v, out);
    }
}